// Round 1
// baseline (253.945 us; speedup 1.0000x reference)
//
#include <hip/hip_runtime.h>
#include <hip/hip_bf16.h>

// Problem: h = x(65536x512) @ W^T(512x256) + bias_lin ; GroupNorm(8 groups of 32)
//          ; min over 256 channels -> m[b] ; out[c*B+b] = m[b] + bias[c]
#define B_ROWS 65536
#define K_DIM  512
#define N_DIM  256
#define EPS    1e-5f
#define MTILE  64
#define LDS_STRIDE 264   // 256 k-half + 8 pad (bf16 elems); 528B rows -> 2-way bank alias max (free)

using short8  = __attribute__((ext_vector_type(8))) short;
using floatx4 = __attribute__((ext_vector_type(4))) float;

__device__ __forceinline__ unsigned short f2bf(float f) {
    unsigned u = __builtin_bit_cast(unsigned, f);
    u += 0x7FFFu + ((u >> 16) & 1u);     // RNE
    return (unsigned short)(u >> 16);
}

// Pack W (256x512 fp32) into bf16 MFMA B-fragment order:
// P[((nt*16 + kk)*64 + lane)*8 + j] = bf16(W[nt*16 + (lane&15)][kk*32 + (lane>>4)*8 + j])
// -> in the GEMM each lane loads its 16B fragment contiguously (1KB/wave, coalesced, L2-resident).
__global__ __launch_bounds__(64) void pack_w(const float* __restrict__ W,
                                             unsigned short* __restrict__ P) {
    int b    = blockIdx.x;           // 0..255
    int nt   = b >> 4, kk = b & 15;
    int lane = threadIdx.x;
    int l15  = lane & 15, quad = lane >> 4;
    const float* src = W + (size_t)(nt * 16 + l15) * K_DIM + kk * 32 + quad * 8;
    short8 v;
#pragma unroll
    for (int j = 0; j < 8; ++j) v[j] = (short)f2bf(src[j]);
    *(short8*)(P + ((size_t)(nt * 16 + kk) * 64 + lane) * 8) = v;
}

// Fused GEMM(bf16 MFMA) + bias + GroupNorm + channel-min. One block = 64 rows x all 256 cols.
// Wave w owns cols [64w, 64w+64) = groups 2w, 2w+1 (each 32-ch group entirely in-wave).
__global__ __launch_bounds__(256) void gemm_gn_min(
    const float* __restrict__ X, const unsigned short* __restrict__ P,
    const float* __restrict__ bias_lin, const float* __restrict__ wgn,
    const float* __restrict__ bgn, float* __restrict__ Mout)
{
    __shared__ unsigned short Ash[MTILE * LDS_STRIDE];   // 33792 B
    __shared__ float sm_min[4][MTILE];                   // 1024 B

    const int tid  = threadIdx.x;
    const int wave = tid >> 6, lane = tid & 63;
    const int l15  = lane & 15, quad = lane >> 4;
    const size_t row0 = (size_t)blockIdx.x * MTILE;

    floatx4 acc[4][4] = {};   // [row-tile][col-tile], D: col=lane&15, row=quad*4+reg

    for (int kh = 0; kh < 2; ++kh) {           // two K=256 halves staged in LDS
        if (kh) __syncthreads();               // all waves done reading previous half
        // stage 64 rows x 256 k : fp32 global (coalesced float4) -> bf16 LDS
        for (int i = tid; i < MTILE * 64; i += 256) {
            int r = i >> 6, c4 = (i & 63) << 2;
            const float4 f = *(const float4*)(X + (row0 + r) * K_DIM + kh * 256 + c4);
            ushort4 h;
            h.x = f2bf(f.x); h.y = f2bf(f.y); h.z = f2bf(f.z); h.w = f2bf(f.w);
            *(ushort4*)(&Ash[r * LDS_STRIDE + c4]) = h;
        }
        __syncthreads();

#pragma unroll
        for (int kk = 0; kk < 8; ++kk) {
            const int kkg = kh * 8 + kk;
            short8 a[4], b[4];
#pragma unroll
            for (int rt = 0; rt < 4; ++rt)
                a[rt] = *(const short8*)&Ash[(rt * 16 + l15) * LDS_STRIDE + kk * 32 + quad * 8];
#pragma unroll
            for (int ct = 0; ct < 4; ++ct) {
                int nt = wave * 4 + ct;
                b[ct] = *(const short8*)(P + (((size_t)nt * 16 + kkg) * 64 + lane) * 8);
            }
#pragma unroll
            for (int rt = 0; rt < 4; ++rt)
#pragma unroll
                for (int ct = 0; ct < 4; ++ct)
                    acc[rt][ct] = __builtin_amdgcn_mfma_f32_16x16x32_bf16(
                        a[rt], b[ct], acc[rt][ct], 0, 0, 0);
        }
    }

    // epilogue: per-column params (16 distinct per wave -> broadcasty L2 loads)
    float bl[4], wg[4], bg[4];
#pragma unroll
    for (int ct = 0; ct < 4; ++ct) {
        int col = wave * 64 + ct * 16 + l15;
        bl[ct] = bias_lin[col]; wg[ct] = wgn[col]; bg[ct] = bgn[col];
    }

#pragma unroll
    for (int rt = 0; rt < 4; ++rt) {
#pragma unroll
        for (int reg = 0; reg < 4; ++reg) {
            float v[4];
#pragma unroll
            for (int ct = 0; ct < 4; ++ct) v[ct] = acc[rt][ct][reg] + bl[ct];
            float rmin = 1e30f;
#pragma unroll
            for (int h = 0; h < 2; ++h) {   // two 32-ch groups per wave (ct pairs)
                float va = v[2 * h], vb = v[2 * h + 1];
                float s = va + vb, ss = va * va + vb * vb;
#pragma unroll
                for (int m = 1; m < 16; m <<= 1) {   // 16-lane butterfly (stays in group)
                    s  += __shfl_xor(s, m);
                    ss += __shfl_xor(ss, m);
                }
                float mean = s * (1.0f / 32.0f);
                float var  = ss * (1.0f / 32.0f) - mean * mean;
                float inv  = rsqrtf(var + EPS);
                float ga = (va - mean) * inv * wg[2 * h]     + bg[2 * h];
                float gb = (vb - mean) * inv * wg[2 * h + 1] + bg[2 * h + 1];
                float mn = fminf(ga, gb);
#pragma unroll
                for (int m = 1; m < 16; m <<= 1) mn = fminf(mn, __shfl_xor(mn, m));
                rmin = fminf(rmin, mn);
            }
            if (l15 == 0) sm_min[wave][rt * 16 + quad * 4 + reg] = rmin;
        }
    }
    __syncthreads();
    if (tid < MTILE) {
        float m0 = fminf(fminf(sm_min[0][tid], sm_min[1][tid]),
                         fminf(sm_min[2][tid], sm_min[3][tid]));
        Mout[row0 + tid] = m0;
    }
}

// out[c*B + b] = m[b] + bias[c]; float4 coalesced stores, m + bias L2-resident.
__global__ __launch_bounds__(256) void bcast(const float* __restrict__ Mv,
                                             const float* __restrict__ bias,
                                             float* __restrict__ out) {
    const int c  = blockIdx.y;
    const int b0 = (blockIdx.x * 256 + threadIdx.x) * 4;
    const float bc = bias[c];
    float4 m = *(const float4*)(Mv + b0);
    float4 o;
    o.x = m.x + bc; o.y = m.y + bc; o.z = m.z + bc; o.w = m.w + bc;
    *(float4*)(out + (size_t)c * B_ROWS + b0) = o;
}

extern "C" void kernel_launch(void* const* d_in, const int* in_sizes, int n_in,
                              void* d_out, int out_size, void* d_ws, size_t ws_size,
                              hipStream_t stream) {
    const float* x    = (const float*)d_in[0];
    const float* w    = (const float*)d_in[1];
    const float* bl   = (const float*)d_in[2];
    const float* wg   = (const float*)d_in[3];
    const float* bg   = (const float*)d_in[4];
    const float* bias = (const float*)d_in[5];

    unsigned short* P  = (unsigned short*)d_ws;                  // 256 KB packed bf16 W
    float*          Mv = (float*)((char*)d_ws + 256 * 1024);     // 256 KB per-row mins
    float*          out = (float*)d_out;

    hipLaunchKernelGGL(pack_w, dim3(256), dim3(64), 0, stream, w, P);
    hipLaunchKernelGGL(gemm_gn_min, dim3(B_ROWS / MTILE), dim3(256), 0, stream,
                       x, P, bl, wg, bg, Mv);
    hipLaunchKernelGGL(bcast, dim3(B_ROWS / 1024, N_DIM), dim3(256), 0, stream,
                       Mv, bias, out);
}